// Round 4
// baseline (5567.936 us; speedup 1.0000x reference)
//
#include <hip/hip_runtime.h>

#define Bb 2
#define Nn 256
#define Dd 128
#define Rr 32

typedef unsigned short u16;
typedef unsigned int   u32;
typedef __attribute__((ext_vector_type(8))) short bf16x8;
typedef __attribute__((ext_vector_type(4))) float f32x4;

__device__ __forceinline__ short f2bfs(float f){
  u32 u = __float_as_uint(f);
  u += 0x7FFFu + ((u >> 16) & 1u);   // RNE
  return (short)(u >> 16);
}
__device__ __forceinline__ u16 f2bf(float f){
  u32 u = __float_as_uint(f);
  u += 0x7FFFu + ((u >> 16) & 1u);
  return (u16)(u >> 16);
}
__device__ __forceinline__ float bf2f(u16 u){
  return __uint_as_float(((u32)u) << 16);
}

// ---- kernel 1: h = node_s @ src_w  (fp32) ----------------------------------
__global__ __launch_bounds__(128) void hproj_kernel(
    const float* __restrict__ node_s, const float* __restrict__ src_w,
    float* __restrict__ h_out){
  __shared__ float s_row[Dd];
  const int bi = blockIdx.x, d = threadIdx.x;
  s_row[d] = node_s[(size_t)bi*Dd + d];
  __syncthreads();
  float acc = 0.f;
  #pragma unroll 8
  for (int k=0;k<Dd;k++) acc += s_row[k]*src_w[k*Dd + d];
  h_out[(size_t)bi*Dd + d] = acc;
}

// ---- kernel 2: MFMA radial MLPs + fused message accumulation ---------------
__global__ __launch_bounds__(256,2) void se3_mfma(
    const float* __restrict__ node_v,
    const float* __restrict__ rbf,
    const float* __restrict__ r_hat,
    const float* __restrict__ maskp,
    const float* __restrict__ r0w1, const float* __restrict__ r0b1,
    const float* __restrict__ r0w2, const float* __restrict__ r0b2,
    const float* __restrict__ r1w1, const float* __restrict__ r1b1,
    const float* __restrict__ r1w2, const float* __restrict__ r1b2,
    const float* __restrict__ r2w1, const float* __restrict__ r2b1,
    const float* __restrict__ r2w2, const float* __restrict__ r2b2,
    const float* __restrict__ r3w1, const float* __restrict__ r3b1,
    const float* __restrict__ r3w2, const float* __restrict__ r3b2,
    const float* __restrict__ ln_g, const float* __restrict__ ln_b,
    const float* __restrict__ out_w, const float* __restrict__ out_b,
    const float* __restrict__ v_scale, const float* __restrict__ t_scale,
    const float* __restrict__ h_ws,
    float* __restrict__ out_s, float* __restrict__ out_v, float* __restrict__ out_t)
{
  // LDS: 34816 + 1024 + 3072 + 5120 + 10240 + 512 + 512 + 1024 + 8 = 56328 B
  __shared__ u16   s_hid[128*136];      // hidden, half of j, stride 136 u16
  __shared__ float s_mask[Nn];
  __shared__ float s_Y1[Nn*3];
  __shared__ float s_Y2[Nn*5];
  __shared__ float s_red[2][Dd][10];
  __shared__ float s_msg[Dd];
  __shared__ float s_xn[Dd];
  __shared__ float s_part[2*Dd];
  __shared__ float s_mv[2];

  const int tid  = threadIdx.x;
  const int bi   = blockIdx.x;            // b*N + i
  const int b    = bi >> 8;
  const int lane = tid & 63;
  const int w    = tid >> 6;              // wave 0..3
  const int q    = lane >> 4;             // quad
  const int cc   = lane & 15;
  const int ng   = w & 1;                 // n-group: cols [64*ng, 64*ng+64)
  const int mg   = w >> 1;                // m-group
  const int dbase= ng*64;

  // ---- setup: mask, Y1, Y2 (one j per thread) ----
  {
    int j = tid;
    size_t pidx = (size_t)bi*Nn + j;
    s_mask[j] = maskp[pidx];
    float x = r_hat[pidx*3+0];
    float y = r_hat[pidx*3+1];
    float z = r_hat[pidx*3+2];
    const float SQ3=1.7320508075688772f;   // sqrt(3)
    const float C15=3.8729833462074170f;   // sqrt(15)
    const float C5H=1.1180339887498949f;   // 0.5*sqrt(5)
    s_Y1[j*3+0]=SQ3*x; s_Y1[j*3+1]=SQ3*y; s_Y1[j*3+2]=SQ3*z;
    s_Y2[j*5+0]=C15*x*y;
    s_Y2[j*5+1]=C15*y*z;
    s_Y2[j*5+2]=C5H*(3.f*z*z-1.f);
    s_Y2[j*5+3]=C15*x*z;
    s_Y2[j*5+4]=0.5f*C15*(x*x-y*y);
  }

  const float* W1a[4]={r0w1,r1w1,r2w1,r3w1};
  const float* B1a[4]={r0b1,r1b1,r2b1,r3b1};
  const float* W2a[4]={r0w2,r1w2,r2w2,r3w2};
  const float* B2a[4]={r0b2,r1b2,r2b2,r3b2};

  const float* rbf_blk = rbf + (size_t)bi*Nn*Rr;
  const float* hb      = h_ws + (size_t)b*Nn*Dd;

  // node_v[b,i,c,d] for this wave's 4 n-tiles
  float vv0[4], vv1[4], vv2[4];
  {
    const float* nv = node_v + (size_t)bi*3*Dd;
    #pragma unroll
    for (int nt=0;nt<4;nt++){
      int dd = dbase+nt*16+cc;
      vv0[nt]=nv[0*Dd+dd];
      vv1[nt]=nv[1*Dd+dd];
      vv2[nt]=nv[2*Dd+dd];
    }
  }

  float a_ms[4]={0.f,0.f,0.f,0.f};
  float a_mv[4]={0.f,0.f,0.f,0.f};
  float a_dv[3][4]={};
  float a_dt[5][4]={};

  const f32x4 zf = {0.f,0.f,0.f,0.f};

  #pragma unroll 1
  for (int p=0;p<4;p++){
    // ---- load w1/w2 B-fragments for this MLP into VGPRs (fp32 -> bf16) ----
    bf16x8 w1f[4];
    bf16x8 w2f[4][4];
    float  b1v[4], b2v[4];
    const float* W1p=W1a[p]; const float* W2p=W2a[p];
    #pragma unroll
    for (int nt=0;nt<4;nt++){
      int dd = dbase+nt*16+cc;
      b1v[nt]=B1a[p][dd];
      b2v[nt]=B2a[p][dd];
      #pragma unroll
      for (int jj=0;jj<8;jj++){
        w1f[nt][jj] = f2bfs(W1p[(q*8+jj)*Dd + dd]);
      }
      #pragma unroll
      for (int ks=0;ks<4;ks++){
        #pragma unroll
        for (int jj=0;jj<8;jj++){
          w2f[nt][ks][jj] = f2bfs(W2p[(ks*32+q*8+jj)*Dd + dd]);
        }
      }
    }

    #pragma unroll 1
    for (int hh=0; hh<2; hh++){        // j halves: [0,128), [128,256)
      __syncthreads();                 // prior GEMM2 reads of s_hid done
      // ---- GEMM1: rbf @ w1, SiLU, -> s_hid (bf16) ----
      #pragma unroll
      for (int t=0;t<4;t++){
        int mloc = mg*4+t;                       // local m-tile 0..7
        int jrow = (hh*8+mloc)*16 + cc;          // global j row for A-frag
        const float* rp = rbf_blk + (size_t)jrow*Rr + q*8;
        f32x4 ra0 = *(const f32x4*)rp;
        f32x4 ra1 = *(const f32x4*)(rp+4);
        bf16x8 raf;
        raf[0]=f2bfs(ra0[0]); raf[1]=f2bfs(ra0[1]);
        raf[2]=f2bfs(ra0[2]); raf[3]=f2bfs(ra0[3]);
        raf[4]=f2bfs(ra1[0]); raf[5]=f2bfs(ra1[1]);
        raf[6]=f2bfs(ra1[2]); raf[7]=f2bfs(ra1[3]);
        #pragma unroll
        for (int nt=0;nt<4;nt++){
          f32x4 hc = __builtin_amdgcn_mfma_f32_16x16x32_bf16(raf, w1f[nt], zf, 0,0,0);
          #pragma unroll
          for (int r=0;r<4;r++){
            float x  = hc[r] + b1v[nt];
            float sg = 1.f/(1.f + __expf(-x));
            float s  = x*sg;                       // SiLU
            int jl = mloc*16 + q*4 + r;            // C layout: row=quad*4+reg
            s_hid[jl*136 + dbase + nt*16 + cc] = f2bf(s);
          }
        }
      }
      __syncthreads();                 // hidden ready
      // ---- GEMM2: hidden @ w2, + accumulate messages ----
      #pragma unroll
      for (int t=0;t<4;t++){
        int mloc = mg*4+t;
        bf16x8 af[4];
        #pragma unroll
        for (int ks=0;ks<4;ks++){
          af[ks] = *(const bf16x8*)&s_hid[(mloc*16+cc)*136 + ks*32 + q*8];
        }
        #pragma unroll
        for (int nt=0;nt<4;nt++){
          f32x4 c2 = zf;
          #pragma unroll
          for (int ks=0;ks<4;ks++){
            c2 = __builtin_amdgcn_mfma_f32_16x16x32_bf16(af[ks], w2f[nt][ks], c2, 0,0,0);
          }
          int dd = dbase+nt*16+cc;
          #pragma unroll
          for (int r=0;r<4;r++){
            int j     = hh*128 + mloc*16 + q*4 + r;
            float rad = c2[r] + b2v[nt];
            float mk  = s_mask[j];
            if (p==0){
              float hv = hb[(size_t)j*Dd + dd];
              a_ms[nt] += hv*mk*rad;
            } else if (p==1){
              float hv = hb[(size_t)j*Dd + dd];
              float a  = hv*mk*rad;
              a_dv[0][nt] += a*s_Y1[j*3+0];
              a_dv[1][nt] += a*s_Y1[j*3+1];
              a_dv[2][nt] += a*s_Y1[j*3+2];
            } else if (p==2){
              float hv = hb[(size_t)j*Dd + dd];
              float a  = hv*mk*rad;
              a_dt[0][nt] += a*s_Y2[j*5+0];
              a_dt[1][nt] += a*s_Y2[j*5+1];
              a_dt[2][nt] += a*s_Y2[j*5+2];
              a_dt[3][nt] += a*s_Y2[j*5+3];
              a_dt[4][nt] += a*s_Y2[j*5+4];
            } else {
              float dot = vv0[nt]*s_Y1[j*3+0] + vv1[nt]*s_Y1[j*3+1] + vv2[nt]*s_Y1[j*3+2];
              a_mv[nt] += dot*mk*rad;
            }
          }
        }
      }
    }
  }

  // ---- reduce over quads (shfl) then across m-group waves (LDS) ----
  #pragma unroll
  for (int nt=0;nt<4;nt++){
    float vals[10];
    vals[0]=a_ms[nt];
    vals[1]=a_dv[0][nt]; vals[2]=a_dv[1][nt]; vals[3]=a_dv[2][nt];
    vals[4]=a_dt[0][nt]; vals[5]=a_dt[1][nt]; vals[6]=a_dt[2][nt];
    vals[7]=a_dt[3][nt]; vals[8]=a_dt[4][nt];
    vals[9]=a_mv[nt];
    #pragma unroll
    for (int k=0;k<10;k++){
      float v = vals[k];
      v += __shfl_xor(v,16);
      v += __shfl_xor(v,32);
      if (lane<16) s_red[mg][dbase+nt*16+lane][k]=v;
    }
  }
  __syncthreads();

  // ---- delta_v / delta_t outputs + msg for LN ----
  if (tid < Dd){
    int d = tid;
    float msv = s_red[0][d][0]+s_red[1][d][0];
    float mvv = s_red[0][d][9]+s_red[1][d][9];
    s_msg[d] = msv+mvv;
    float vs = v_scale[d];
    float ts = t_scale[d];
    size_t ovb = (size_t)bi*3*Dd + d;
    #pragma unroll
    for (int c2=0;c2<3;c2++)
      out_v[ovb + (size_t)c2*Dd] = (s_red[0][d][1+c2]+s_red[1][d][1+c2])*vs;
    size_t otb = (size_t)bi*5*Dd + d;
    #pragma unroll
    for (int c2=0;c2<5;c2++)
      out_t[otb + (size_t)c2*Dd] = (s_red[0][d][4+c2]+s_red[1][d][4+c2])*ts;
  }
  __syncthreads();

  // ---- LayerNorm stats (wave 0), biased var, guarded ----
  if (tid < 64){
    float a0=s_msg[tid], a1=s_msg[tid+64];
    float s1=a0+a1, s2=a0*a0+a1*a1;
    #pragma unroll
    for (int off=1;off<64;off<<=1){
      s1 += __shfl_xor(s1,off);
      s2 += __shfl_xor(s2,off);
    }
    if (tid==0){
      float m   = s1*(1.f/Dd);
      float var = fmaxf(s2*(1.f/Dd) - m*m, 0.f);
      s_mv[0]=m;
      s_mv[1]=rsqrtf(var+1e-5f);
    }
  }
  __syncthreads();
  if (tid < Dd)
    s_xn[tid] = (s_msg[tid]-s_mv[0])*s_mv[1]*ln_g[tid] + ln_b[tid];
  __syncthreads();

  // ---- delta_s = xn @ out_w + out_b ----
  {
    int dp = tid & 127, seg = tid >> 7;
    float pa = 0.f;
    #pragma unroll 8
    for (int k=seg*64;k<seg*64+64;k++)
      pa += s_xn[k]*out_w[k*Dd+dp];
    s_part[seg*Dd+dp]=pa;
  }
  __syncthreads();
  if (tid < Dd)
    out_s[(size_t)bi*Dd+tid] = s_part[tid]+s_part[Dd+tid]+out_b[tid];
}

extern "C" void kernel_launch(void* const* d_in, const int* in_sizes, int n_in,
                              void* d_out, int out_size, void* d_ws, size_t ws_size,
                              hipStream_t stream) {
  const float* node_s = (const float*)d_in[0];
  const float* node_v = (const float*)d_in[1];
  // d_in[2] = node_t (unused by reference)
  const float* rbf    = (const float*)d_in[3];
  const float* r_hat  = (const float*)d_in[4];
  const float* maskp  = (const float*)d_in[5];
  const float* r0w1=(const float*)d_in[6],  *r0b1=(const float*)d_in[7];
  const float* r0w2=(const float*)d_in[8],  *r0b2=(const float*)d_in[9];
  const float* r1w1=(const float*)d_in[10], *r1b1=(const float*)d_in[11];
  const float* r1w2=(const float*)d_in[12], *r1b2=(const float*)d_in[13];
  const float* r2w1=(const float*)d_in[14], *r2b1=(const float*)d_in[15];
  const float* r2w2=(const float*)d_in[16], *r2b2=(const float*)d_in[17];
  const float* r3w1=(const float*)d_in[18], *r3b1=(const float*)d_in[19];
  const float* r3w2=(const float*)d_in[20], *r3b2=(const float*)d_in[21];
  const float* src_w  =(const float*)d_in[22];
  const float* ln_g   =(const float*)d_in[23];
  const float* ln_b   =(const float*)d_in[24];
  const float* out_w  =(const float*)d_in[25];
  const float* out_b  =(const float*)d_in[26];
  const float* v_scale=(const float*)d_in[27];
  const float* t_scale=(const float*)d_in[28];

  float* h_ws = (float*)d_ws;                    // 512*128 f32 = 256 KiB
  float* out_s = (float*)d_out;
  float* out_v = out_s + (size_t)Bb*Nn*Dd;
  float* out_t = out_v + (size_t)Bb*Nn*3*Dd;

  hproj_kernel<<<dim3(Bb*Nn), dim3(Dd), 0, stream>>>(node_s, src_w, h_ws);
  se3_mfma<<<dim3(Bb*Nn), dim3(256), 0, stream>>>(
      node_v, rbf, r_hat, maskp,
      r0w1,r0b1,r0w2,r0b2, r1w1,r1b1,r1w2,r1b2,
      r2w1,r2b1,r2w2,r2b2, r3w1,r3b1,r3w2,r3b2,
      ln_g, ln_b, out_w, out_b, v_scale, t_scale,
      h_ws, out_s, out_v, out_t);
}

// Round 5
// 300.569 us; speedup vs baseline: 18.5247x; 18.5247x over previous
//
#include <hip/hip_runtime.h>

#define Bb 2
#define Nn 256
#define Dd 128
#define Rr 32

typedef unsigned short u16;
typedef unsigned int   u32;
typedef __attribute__((ext_vector_type(8))) short bf16x8;
typedef __attribute__((ext_vector_type(4))) short bf16x4;
typedef __attribute__((ext_vector_type(4))) float f32x4;

__device__ __forceinline__ short f2bfs(float f){
  u32 u = __float_as_uint(f);
  u += 0x7FFFu + ((u >> 16) & 1u);   // RNE
  return (short)(u >> 16);
}
__device__ __forceinline__ u16 f2bf(float f){
  u32 u = __float_as_uint(f);
  u += 0x7FFFu + ((u >> 16) & 1u);
  return (u16)(u >> 16);
}

// ---- kernel 1: h = node_s @ src_w  (fp32) ----------------------------------
__global__ __launch_bounds__(128) void hproj_kernel(
    const float* __restrict__ node_s, const float* __restrict__ src_w,
    float* __restrict__ h_out){
  __shared__ float s_row[Dd];
  const int bi = blockIdx.x, d = threadIdx.x;
  s_row[d] = node_s[(size_t)bi*Dd + d];
  __syncthreads();
  float acc = 0.f;
  #pragma unroll 8
  for (int k=0;k<Dd;k++) acc += s_row[k]*src_w[k*Dd + d];
  h_out[(size_t)bi*Dd + d] = acc;
}

// ---- kernel 2: MFMA radial MLPs + fused message accumulation ---------------
// One block per (b,i). 4 waves; wave w owns d-cols [w*32, w*32+32) (nt=0,1).
// All waves cover all m-tiles (j rows). Low register design: ~110 VGPR live.
__global__ __launch_bounds__(256,2) void se3_mfma2(
    const float* __restrict__ node_v,
    const float* __restrict__ rbf,
    const float* __restrict__ r_hat,
    const float* __restrict__ maskp,
    const float* __restrict__ r0w1, const float* __restrict__ r0b1,
    const float* __restrict__ r0w2, const float* __restrict__ r0b2,
    const float* __restrict__ r1w1, const float* __restrict__ r1b1,
    const float* __restrict__ r1w2, const float* __restrict__ r1b2,
    const float* __restrict__ r2w1, const float* __restrict__ r2b1,
    const float* __restrict__ r2w2, const float* __restrict__ r2b2,
    const float* __restrict__ r3w1, const float* __restrict__ r3b1,
    const float* __restrict__ r3w2, const float* __restrict__ r3b2,
    const float* __restrict__ ln_g, const float* __restrict__ ln_b,
    const float* __restrict__ out_w, const float* __restrict__ out_b,
    const float* __restrict__ v_scale, const float* __restrict__ t_scale,
    const float* __restrict__ h_ws,
    float* __restrict__ out_s, float* __restrict__ out_v, float* __restrict__ out_t)
{
  // LDS total = 49,160 B
  __shared__ u16   s_rbf[Nn*40];       // 20480 B: rbf bf16, row stride 40 u16
  __shared__ u16   s_hid[64*136];      // 17408 B: hidden for 64-j chunk
  __shared__ float s_Y1[Nn*3];         // 3072 B
  __shared__ float s_Y2[Nn*5];         // 5120 B
  __shared__ float s_mask[Nn];         // 1024 B
  __shared__ float s_msg[Dd];          // 512 B
  __shared__ float s_xn[Dd];           // 512 B
  __shared__ float s_part[2*Dd];       // 1024 B
  __shared__ float s_mv[2];            // 8 B

  const int tid  = threadIdx.x;
  const int bi   = blockIdx.x;            // b*N + i
  const int b    = bi >> 8;
  const int lane = tid & 63;
  const int w    = tid >> 6;              // wave 0..3
  const int q    = lane >> 4;             // quad
  const int cc   = lane & 15;
  const int dbase= w*32;                  // this wave's d-col base

  // ---- setup: mask, Y1, Y2 (one j per thread) ----
  {
    int j = tid;
    size_t pidx = (size_t)bi*Nn + j;
    s_mask[j] = maskp[pidx];
    float x = r_hat[pidx*3+0];
    float y = r_hat[pidx*3+1];
    float z = r_hat[pidx*3+2];
    const float SQ3=1.7320508075688772f;   // sqrt(3)
    const float C15=3.8729833462074170f;   // sqrt(15)
    const float C5H=1.1180339887498949f;   // 0.5*sqrt(5)
    s_Y1[j*3+0]=SQ3*x; s_Y1[j*3+1]=SQ3*y; s_Y1[j*3+2]=SQ3*z;
    s_Y2[j*5+0]=C15*x*y;
    s_Y2[j*5+1]=C15*y*z;
    s_Y2[j*5+2]=C5H*(3.f*z*z-1.f);
    s_Y2[j*5+3]=C15*x*z;
    s_Y2[j*5+4]=0.5f*C15*(x*x-y*y);
  }

  const float* rbf_blk = rbf + (size_t)bi*Nn*Rr;
  const float* hb      = h_ws + (size_t)b*Nn*Dd;

  // ---- stage all rbf rows as bf16 into LDS (once per block) ----
  for (int idx=tid; idx<Nn*Rr; idx+=256){
    int j = idx >> 5, r = idx & 31;
    s_rbf[j*40 + r] = f2bf(rbf_blk[idx]);
  }

  // node_v[b,i,c,d] for this wave's 2 n-tiles
  float vv0[2], vv1[2], vv2[2];
  {
    const float* nv = node_v + (size_t)bi*3*Dd;
    #pragma unroll
    for (int nt=0;nt<2;nt++){
      int dd = dbase+nt*16+cc;
      vv0[nt]=nv[0*Dd+dd];
      vv1[nt]=nv[1*Dd+dd];
      vv2[nt]=nv[2*Dd+dd];
    }
  }

  float a_ms[2]={0.f,0.f};
  float a_mv[2]={0.f,0.f};
  float a_dv[3][2]={};
  float a_dt[5][2]={};

  const f32x4 zf = {0.f,0.f,0.f,0.f};

  #pragma unroll 1
  for (int p=0;p<4;p++){
    // ternary selects -> SGPR cmov, no private array
    const float* W1p = (p==0)?r0w1:(p==1)?r1w1:(p==2)?r2w1:r3w1;
    const float* B1p = (p==0)?r0b1:(p==1)?r1b1:(p==2)?r2b1:r3b1;
    const float* W2p = (p==0)?r0w2:(p==1)?r1w2:(p==2)?r2w2:r3w2;
    const float* B2p = (p==0)?r0b2:(p==1)?r1b2:(p==2)?r2b2:r3b2;

    // ---- per-p weight fragments: w1f[2]=8 VGPR, w2f[2][4]=32 VGPR ----
    bf16x8 w1f[2];
    bf16x8 w2f[2][4];
    float  b1v[2], b2v[2];
    #pragma unroll
    for (int nt=0;nt<2;nt++){
      int dd = dbase+nt*16+cc;
      b1v[nt]=B1p[dd];
      b2v[nt]=B2p[dd];
      #pragma unroll
      for (int jj=0;jj<8;jj++)
        w1f[nt][jj] = f2bfs(W1p[(q*8+jj)*Dd + dd]);
      #pragma unroll
      for (int ks=0;ks<4;ks++){
        #pragma unroll
        for (int jj=0;jj<8;jj++)
          w2f[nt][ks][jj] = f2bfs(W2p[(ks*32+q*8+jj)*Dd + dd]);
      }
    }

    #pragma unroll 1
    for (int ch=0; ch<4; ch++){          // 4 chunks of 64 j
      __syncthreads();                   // protect s_hid (prev GEMM2) / s_rbf ready
      // ---- GEMM1: rbf @ w1 -> SiLU -> s_hid (bf16) ----
      #pragma unroll
      for (int m=0;m<4;m++){
        const u16* ap = &s_rbf[(ch*64 + m*16 + cc)*40 + q*8];
        bf16x4 lo = *(const bf16x4*)ap;
        bf16x4 hi = *(const bf16x4*)(ap+4);
        bf16x8 raf = {lo[0],lo[1],lo[2],lo[3],hi[0],hi[1],hi[2],hi[3]};
        #pragma unroll
        for (int nt=0;nt<2;nt++){
          f32x4 hc = __builtin_amdgcn_mfma_f32_16x16x32_bf16(raf, w1f[nt], zf, 0,0,0);
          #pragma unroll
          for (int r=0;r<4;r++){
            float x  = hc[r] + b1v[nt];
            float sg = 1.f/(1.f + __expf(-x));
            int jl = m*16 + q*4 + r;     // C layout: row=q*4+r, col=cc
            s_hid[jl*136 + dbase + nt*16 + cc] = f2bf(x*sg);
          }
        }
      }
      __syncthreads();                   // hidden ready
      // ---- GEMM2: hidden @ w2 + fused accumulate ----
      #pragma unroll
      for (int m=0;m<4;m++){
        bf16x8 af[4];
        #pragma unroll
        for (int ks=0;ks<4;ks++)
          af[ks] = *(const bf16x8*)&s_hid[(m*16+cc)*136 + ks*32 + q*8];
        #pragma unroll
        for (int nt=0;nt<2;nt++){
          f32x4 c2 = zf;
          #pragma unroll
          for (int ks=0;ks<4;ks++)
            c2 = __builtin_amdgcn_mfma_f32_16x16x32_bf16(af[ks], w2f[nt][ks], c2, 0,0,0);
          int dd = dbase+nt*16+cc;
          #pragma unroll
          for (int r=0;r<4;r++){
            int j     = ch*64 + m*16 + q*4 + r;
            float rad = (c2[r] + b2v[nt]) * s_mask[j];
            if (p==0){
              a_ms[nt] += hb[(size_t)j*Dd + dd]*rad;
            } else if (p==1){
              float a = hb[(size_t)j*Dd + dd]*rad;
              a_dv[0][nt] += a*s_Y1[j*3+0];
              a_dv[1][nt] += a*s_Y1[j*3+1];
              a_dv[2][nt] += a*s_Y1[j*3+2];
            } else if (p==2){
              float a = hb[(size_t)j*Dd + dd]*rad;
              a_dt[0][nt] += a*s_Y2[j*5+0];
              a_dt[1][nt] += a*s_Y2[j*5+1];
              a_dt[2][nt] += a*s_Y2[j*5+2];
              a_dt[3][nt] += a*s_Y2[j*5+3];
              a_dt[4][nt] += a*s_Y2[j*5+4];
            } else {
              float dot = vv0[nt]*s_Y1[j*3+0] + vv1[nt]*s_Y1[j*3+1] + vv2[nt]*s_Y1[j*3+2];
              a_mv[nt] += dot*rad;
            }
          }
        }
      }
    }
  }

  // ---- quad reduce (q dimension): each wave owns its d-cols exclusively ----
  #pragma unroll
  for (int nt=0;nt<2;nt++){
    float vals[10];
    vals[0]=a_ms[nt];
    vals[1]=a_dv[0][nt]; vals[2]=a_dv[1][nt]; vals[3]=a_dv[2][nt];
    vals[4]=a_dt[0][nt]; vals[5]=a_dt[1][nt]; vals[6]=a_dt[2][nt];
    vals[7]=a_dt[3][nt]; vals[8]=a_dt[4][nt];
    vals[9]=a_mv[nt];
    #pragma unroll
    for (int k=0;k<10;k++){
      float v = vals[k];
      v += __shfl_xor(v,16);
      v += __shfl_xor(v,32);
      vals[k]=v;
    }
    if (lane < 16){
      int d = dbase + nt*16 + lane;
      s_msg[d] = vals[0] + vals[9];
      float vs = v_scale[d], ts = t_scale[d];
      size_t ovb = (size_t)bi*3*Dd + d;
      out_v[ovb + 0*Dd] = vals[1]*vs;
      out_v[ovb + 1*Dd] = vals[2]*vs;
      out_v[ovb + 2*Dd] = vals[3]*vs;
      size_t otb = (size_t)bi*5*Dd + d;
      #pragma unroll
      for (int c2=0;c2<5;c2++)
        out_t[otb + (size_t)c2*Dd] = vals[4+c2]*ts;
    }
  }
  __syncthreads();

  // ---- LayerNorm stats (wave 0), biased var, guarded ----
  if (tid < 64){
    float a0=s_msg[tid], a1=s_msg[tid+64];
    float s1=a0+a1, s2=a0*a0+a1*a1;
    #pragma unroll
    for (int off=1;off<64;off<<=1){
      s1 += __shfl_xor(s1,off);
      s2 += __shfl_xor(s2,off);
    }
    if (tid==0){
      float m   = s1*(1.f/Dd);
      float var = fmaxf(s2*(1.f/Dd) - m*m, 0.f);
      s_mv[0]=m;
      s_mv[1]=rsqrtf(var+1e-5f);
    }
  }
  __syncthreads();
  if (tid < Dd)
    s_xn[tid] = (s_msg[tid]-s_mv[0])*s_mv[1]*ln_g[tid] + ln_b[tid];
  __syncthreads();

  // ---- delta_s = xn @ out_w + out_b ----
  {
    int dp = tid & 127, seg = tid >> 7;
    float pa = 0.f;
    #pragma unroll 8
    for (int k=seg*64;k<seg*64+64;k++)
      pa += s_xn[k]*out_w[k*Dd+dp];
    s_part[seg*Dd+dp]=pa;
  }
  __syncthreads();
  if (tid < Dd)
    out_s[(size_t)bi*Dd+tid] = s_part[tid]+s_part[Dd+tid]+out_b[tid];
}

extern "C" void kernel_launch(void* const* d_in, const int* in_sizes, int n_in,
                              void* d_out, int out_size, void* d_ws, size_t ws_size,
                              hipStream_t stream) {
  const float* node_s = (const float*)d_in[0];
  const float* node_v = (const float*)d_in[1];
  // d_in[2] = node_t (unused by reference)
  const float* rbf    = (const float*)d_in[3];
  const float* r_hat  = (const float*)d_in[4];
  const float* maskp  = (const float*)d_in[5];
  const float* r0w1=(const float*)d_in[6],  *r0b1=(const float*)d_in[7];
  const float* r0w2=(const float*)d_in[8],  *r0b2=(const float*)d_in[9];
  const float* r1w1=(const float*)d_in[10], *r1b1=(const float*)d_in[11];
  const float* r1w2=(const float*)d_in[12], *r1b2=(const float*)d_in[13];
  const float* r2w1=(const float*)d_in[14], *r2b1=(const float*)d_in[15];
  const float* r2w2=(const float*)d_in[16], *r2b2=(const float*)d_in[17];
  const float* r3w1=(const float*)d_in[18], *r3b1=(const float*)d_in[19];
  const float* r3w2=(const float*)d_in[20], *r3b2=(const float*)d_in[21];
  const float* src_w  =(const float*)d_in[22];
  const float* ln_g   =(const float*)d_in[23];
  const float* ln_b   =(const float*)d_in[24];
  const float* out_w  =(const float*)d_in[25];
  const float* out_b  =(const float*)d_in[26];
  const float* v_scale=(const float*)d_in[27];
  const float* t_scale=(const float*)d_in[28];

  float* h_ws = (float*)d_ws;                    // 512*128 f32 = 256 KiB
  float* out_s = (float*)d_out;
  float* out_v = out_s + (size_t)Bb*Nn*Dd;
  float* out_t = out_v + (size_t)Bb*Nn*3*Dd;

  hproj_kernel<<<dim3(Bb*Nn), dim3(Dd), 0, stream>>>(node_s, src_w, h_ws);
  se3_mfma2<<<dim3(Bb*Nn), dim3(256), 0, stream>>>(
      node_v, rbf, r_hat, maskp,
      r0w1,r0b1,r0w2,r0b2, r1w1,r1b1,r1w2,r1b2,
      r2w1,r2b1,r2w2,r2b2, r3w1,r3b1,r3w2,r3b2,
      ln_g, ln_b, out_w, out_b, v_scale, t_scale,
      h_ws, out_s, out_v, out_t);
}

// Round 6
// 197.121 us; speedup vs baseline: 28.2463x; 1.5248x over previous
//
#include <hip/hip_runtime.h>

#define Bb 2
#define Nn 256
#define Dd 128
#define Rr 32

typedef unsigned short u16;
typedef unsigned int   u32;
typedef __attribute__((ext_vector_type(8))) short bf16x8;
typedef __attribute__((ext_vector_type(4))) short bf16x4;
typedef __attribute__((ext_vector_type(4))) float f32x4;
typedef __attribute__((ext_vector_type(2))) u32   u32x2;

__device__ __forceinline__ short f2bfs(float f){
  u32 u = __float_as_uint(f);
  u += 0x7FFFu + ((u >> 16) & 1u);   // RNE
  return (short)(u >> 16);
}
__device__ __forceinline__ u16 f2bf(float f){
  u32 u = __float_as_uint(f);
  u += 0x7FFFu + ((u >> 16) & 1u);
  return (u16)(u >> 16);
}

// ---- kernel 1: h = node_s @ src_w  (fp32) ----------------------------------
__global__ __launch_bounds__(128) void hproj_kernel(
    const float* __restrict__ node_s, const float* __restrict__ src_w,
    float* __restrict__ h_out){
  __shared__ float s_row[Dd];
  const int bi = blockIdx.x, d = threadIdx.x;
  s_row[d] = node_s[(size_t)bi*Dd + d];
  __syncthreads();
  float acc = 0.f;
  #pragma unroll 8
  for (int k=0;k<Dd;k++) acc += s_row[k]*src_w[k*Dd + d];
  h_out[(size_t)bi*Dd + d] = acc;
}

// ---- kernel 2: all-MFMA pipeline, one block per (b,i) ----------------------
// Wave w owns d-cols [w*32, w*32+32). GEMM1 -> SiLU -> GEMM2 -> G -> MFMA
// j-reduction with stacked-Y A operand (rows: 0=mask,1-3=Y1*m,4-8=Y2*m,9=mask).
__global__ __launch_bounds__(256,2) void se3_mfma3(
    const float* __restrict__ node_v,
    const float* __restrict__ rbf,
    const float* __restrict__ r_hat,
    const float* __restrict__ maskp,
    const float* __restrict__ r0w1, const float* __restrict__ r0b1,
    const float* __restrict__ r0w2, const float* __restrict__ r0b2,
    const float* __restrict__ r1w1, const float* __restrict__ r1b1,
    const float* __restrict__ r1w2, const float* __restrict__ r1b2,
    const float* __restrict__ r2w1, const float* __restrict__ r2b1,
    const float* __restrict__ r2w2, const float* __restrict__ r2b2,
    const float* __restrict__ r3w1, const float* __restrict__ r3b1,
    const float* __restrict__ r3w2, const float* __restrict__ r3b2,
    const float* __restrict__ ln_g, const float* __restrict__ ln_b,
    const float* __restrict__ out_w, const float* __restrict__ out_b,
    const float* __restrict__ v_scale, const float* __restrict__ t_scale,
    const float* __restrict__ h_ws,
    float* __restrict__ out_s, float* __restrict__ out_v, float* __restrict__ out_t)
{
  // LDS total = 63,192 B
  __shared__ u16   s_rbf[Nn*36];       // 18432: rbf bf16, row stride 36
  __shared__ u16   s_hid[64*136];      // 17408: hidden for 64-j chunk
  __shared__ u16   s_YT[10*264];       //  5280: rows 0=mask,1-3=Y1*m,4-8=Y2*m,9=mask
  __shared__ u16   s_Y1r[3*264];       //  1584: raw Y1 (for dot MFMA A)
  __shared__ u16   s_G[4*32*72];       // 18432: per-wave G_T[d][j]
  __shared__ float s_msg[Dd];          //   512
  __shared__ float s_xn[Dd];           //   512
  __shared__ float s_part[2*Dd];       //  1024
  __shared__ float s_mv[2];            //     8

  const int tid  = threadIdx.x;
  const int bi   = blockIdx.x;            // b*N + i
  const int b    = bi >> 8;
  const int lane = tid & 63;
  const int w    = tid >> 6;              // wave 0..3
  const int q    = lane >> 4;             // quad
  const int cc   = lane & 15;
  const int dbase= w*32;                  // this wave's d-col base

  // ---- setup: stacked-Y rows (mask folded), raw Y1 ----
  {
    int j = tid;
    size_t pidx = (size_t)bi*Nn + j;
    float mk = maskp[pidx];
    float x = r_hat[pidx*3+0];
    float y = r_hat[pidx*3+1];
    float z = r_hat[pidx*3+2];
    const float SQ3=1.7320508075688772f;   // sqrt(3)
    const float C15=3.8729833462074170f;   // sqrt(15)
    const float C5H=1.1180339887498949f;   // 0.5*sqrt(5)
    float y1a=SQ3*x, y1b=SQ3*y, y1c=SQ3*z;
    s_YT[0*264+j]=f2bf(mk);
    s_YT[1*264+j]=f2bf(y1a*mk);
    s_YT[2*264+j]=f2bf(y1b*mk);
    s_YT[3*264+j]=f2bf(y1c*mk);
    s_YT[4*264+j]=f2bf(C15*x*y*mk);
    s_YT[5*264+j]=f2bf(C15*y*z*mk);
    s_YT[6*264+j]=f2bf(C5H*(3.f*z*z-1.f)*mk);
    s_YT[7*264+j]=f2bf(C15*x*z*mk);
    s_YT[8*264+j]=f2bf(0.5f*C15*(x*x-y*y)*mk);
    s_YT[9*264+j]=f2bf(mk);
    s_Y1r[0*264+j]=f2bf(y1a);
    s_Y1r[1*264+j]=f2bf(y1b);
    s_Y1r[2*264+j]=f2bf(y1c);
  }

  const float* rbf_blk = rbf + (size_t)bi*Nn*Rr;
  const float* hb      = h_ws + (size_t)b*Nn*Dd;

  // ---- stage rbf as bf16 (row stride 36) ----
  for (int idx=tid; idx<Nn*Rr; idx+=256){
    int j = idx >> 5, r = idx & 31;
    s_rbf[j*36 + r] = f2bf(rbf_blk[idx]);
  }

  // ---- node_v B-fragments for the dot MFMA: B[k=c][n=d], k<3 on quad 0 ----
  bf16x8 vBf[2];
  {
    const float* nv = node_v + (size_t)bi*3*Dd;
    #pragma unroll
    for (int nt=0;nt<2;nt++){
      int dd = dbase+nt*16+cc;
      bf16x8 t = {0,0,0,0,0,0,0,0};
      if (q==0){
        t[0]=f2bfs(nv[0*Dd+dd]);
        t[1]=f2bfs(nv[1*Dd+dd]);
        t[2]=f2bfs(nv[2*Dd+dd]);
      }
      vBf[nt]=t;
    }
  }

  const f32x4 zf = {0.f,0.f,0.f,0.f};
  f32x4 accred[2] = {zf, zf};           // rows 0..9 = the 10 reduced outputs

  #pragma unroll 1
  for (int p=0;p<4;p++){
    const float* W1p = (p==0)?r0w1:(p==1)?r1w1:(p==2)?r2w1:r3w1;
    const float* B1p = (p==0)?r0b1:(p==1)?r1b1:(p==2)?r2b1:r3b1;
    const float* W2p = (p==0)?r0w2:(p==1)?r1w2:(p==2)?r2w2:r3w2;
    const float* B2p = (p==0)?r0b2:(p==1)?r1b2:(p==2)?r2b2:r3b2;
    const int lo = (p==0)?0:(p==1)?1:(p==2)?4:9;
    const int hi = (p==0)?0:(p==1)?3:(p==2)?8:9;
    const u32 gmask = (cc>=lo && cc<=hi) ? 0xFFFFFFFFu : 0u;
    const u16* ytrow = &s_YT[(cc<10?cc:9)*264];

    // per-p weight fragments (w1f 8 VGPR, w2f 32 VGPR)
    bf16x8 w1f[2];
    bf16x8 w2f[2][4];
    float  b1v[2], b2v[2];
    #pragma unroll
    for (int nt=0;nt<2;nt++){
      int dd = dbase+nt*16+cc;
      b1v[nt]=B1p[dd];
      b2v[nt]=B2p[dd];
      #pragma unroll
      for (int jj=0;jj<8;jj++)
        w1f[nt][jj] = f2bfs(W1p[(q*8+jj)*Dd + dd]);
      #pragma unroll
      for (int ks=0;ks<4;ks++){
        #pragma unroll
        for (int jj=0;jj<8;jj++)
          w2f[nt][ks][jj] = f2bfs(W2p[(ks*32+q*8+jj)*Dd + dd]);
      }
    }

    #pragma unroll 1
    for (int ch=0; ch<4; ch++){          // 4 chunks of 64 j
      __syncthreads();                   // s_hid free / setup visible
      // ---- GEMM1: rbf @ w1 -> SiLU -> s_hid (bf16) ----
      #pragma unroll
      for (int m=0;m<4;m++){
        const u16* ap = &s_rbf[(ch*64 + m*16 + cc)*36 + q*8];
        bf16x4 lo4 = *(const bf16x4*)ap;
        bf16x4 hi4 = *(const bf16x4*)(ap+4);
        bf16x8 raf = {lo4[0],lo4[1],lo4[2],lo4[3],hi4[0],hi4[1],hi4[2],hi4[3]};
        #pragma unroll
        for (int nt=0;nt<2;nt++){
          f32x4 hc = __builtin_amdgcn_mfma_f32_16x16x32_bf16(raf, w1f[nt], zf, 0,0,0);
          #pragma unroll
          for (int r=0;r<4;r++){
            float x  = hc[r] + b1v[nt];
            float e  = __expf(-x);
            float s  = x*__builtin_amdgcn_rcpf(1.f+e);
            s_hid[(m*16+q*4+r)*136 + dbase + nt*16 + cc] = f2bf(s);
          }
        }
      }
      __syncthreads();                   // hidden ready
      // ---- GEMM2: hidden @ w2 -> G = rad*h (p<3) or rad*dot (p3) ----
      #pragma unroll
      for (int m=0;m<4;m++){
        bf16x8 af[4];
        #pragma unroll
        for (int ks=0;ks<4;ks++)
          af[ks] = *(const bf16x8*)&s_hid[(m*16+cc)*136 + ks*32 + q*8];

        f32x4 dotC[2];
        if (p==3){                       // dot(v, Y1) via K=3 MFMA
          bf16x8 aY = {0,0,0,0,0,0,0,0};
          if (q==0){
            int j = ch*64 + m*16 + cc;
            aY[0]=(short)s_Y1r[0*264+j];
            aY[1]=(short)s_Y1r[1*264+j];
            aY[2]=(short)s_Y1r[2*264+j];
          }
          #pragma unroll
          for (int nt=0;nt<2;nt++)
            dotC[nt] = __builtin_amdgcn_mfma_f32_16x16x32_bf16(aY, vBf[nt], zf, 0,0,0);
        }

        #pragma unroll
        for (int nt=0;nt<2;nt++){
          f32x4 c2 = zf;
          #pragma unroll
          for (int ks=0;ks<4;ks++)
            c2 = __builtin_amdgcn_mfma_f32_16x16x32_bf16(af[ks], w2f[nt][ks], c2, 0,0,0);
          int dd = dbase+nt*16+cc;
          u16 g4[4];
          if (p<3){
            const float* hp = hb + (size_t)(ch*64 + m*16 + q*4)*Dd + dd;
            #pragma unroll
            for (int r=0;r<4;r++)
              g4[r] = f2bf((c2[r]+b2v[nt]) * hp[(size_t)r*Dd]);
          } else {
            #pragma unroll
            for (int r=0;r<4;r++)
              g4[r] = f2bf((c2[r]+b2v[nt]) * dotC[nt][r]);
          }
          u32x2 pk = { (u32)g4[0] | ((u32)g4[1]<<16),
                       (u32)g4[2] | ((u32)g4[3]<<16) };
          *(u32x2*)&s_G[(w*32 + nt*16 + cc)*72 + m*16 + q*4] = pk;
        }
      }
      // ---- j-reduction MFMA (intra-wave: no barrier needed) ----
      #pragma unroll
      for (int ks2=0;ks2<2;ks2++){
        bf16x8 aR = *(const bf16x8*)(ytrow + ch*64 + ks2*32 + q*8);
        u32* arp = (u32*)&aR;
        arp[0]&=gmask; arp[1]&=gmask; arp[2]&=gmask; arp[3]&=gmask;
        #pragma unroll
        for (int nt=0;nt<2;nt++){
          bf16x8 bG = *(const bf16x8*)&s_G[(w*32 + nt*16 + cc)*72 + ks2*32 + q*8];
          accred[nt] = __builtin_amdgcn_mfma_f32_16x16x32_bf16(aR, bG, accred[nt], 0,0,0);
        }
      }
    }
  }

  // ---- scatter accred rows -> outputs / LN inputs ----
  #pragma unroll
  for (int nt=0;nt<2;nt++){
    int d = dbase + nt*16 + cc;
    #pragma unroll
    for (int r=0;r<4;r++){
      int rw = q*4 + r;
      float val = accred[nt][r];
      if (rw==0)      s_msg[d] = val;
      else if (rw<=3) out_v[(size_t)bi*3*Dd + (size_t)(rw-1)*Dd + d] = val*v_scale[d];
      else if (rw<=8) out_t[(size_t)bi*5*Dd + (size_t)(rw-4)*Dd + d] = val*t_scale[d];
      else if (rw==9) s_xn[d] = val;
    }
  }
  __syncthreads();

  // ---- LayerNorm stats (wave 0), biased var, guarded ----
  if (tid < 64){
    float a0=s_msg[tid]+s_xn[tid], a1=s_msg[tid+64]+s_xn[tid+64];
    float s1=a0+a1, s2=a0*a0+a1*a1;
    #pragma unroll
    for (int off=1;off<64;off<<=1){
      s1 += __shfl_xor(s1,off);
      s2 += __shfl_xor(s2,off);
    }
    if (tid==0){
      float m   = s1*(1.f/Dd);
      float var = fmaxf(s2*(1.f/Dd) - m*m, 0.f);
      s_mv[0]=m;
      s_mv[1]=rsqrtf(var+1e-5f);
    }
  }
  __syncthreads();
  if (tid < Dd){
    float msg = s_msg[tid]+s_xn[tid];
    s_xn[tid] = (msg - s_mv[0])*s_mv[1]*ln_g[tid] + ln_b[tid];
  }
  __syncthreads();

  // ---- delta_s = xn @ out_w + out_b ----
  {
    int dp = tid & 127, seg = tid >> 7;
    float pa = 0.f;
    #pragma unroll 8
    for (int k=seg*64;k<seg*64+64;k++)
      pa += s_xn[k]*out_w[k*Dd+dp];
    s_part[seg*Dd+dp]=pa;
  }
  __syncthreads();
  if (tid < Dd)
    out_s[(size_t)bi*Dd+tid] = s_part[tid]+s_part[Dd+tid]+out_b[tid];
}

extern "C" void kernel_launch(void* const* d_in, const int* in_sizes, int n_in,
                              void* d_out, int out_size, void* d_ws, size_t ws_size,
                              hipStream_t stream) {
  const float* node_s = (const float*)d_in[0];
  const float* node_v = (const float*)d_in[1];
  // d_in[2] = node_t (unused by reference)
  const float* rbf    = (const float*)d_in[3];
  const float* r_hat  = (const float*)d_in[4];
  const float* maskp  = (const float*)d_in[5];
  const float* r0w1=(const float*)d_in[6],  *r0b1=(const float*)d_in[7];
  const float* r0w2=(const float*)d_in[8],  *r0b2=(const float*)d_in[9];
  const float* r1w1=(const float*)d_in[10], *r1b1=(const float*)d_in[11];
  const float* r1w2=(const float*)d_in[12], *r1b2=(const float*)d_in[13];
  const float* r2w1=(const float*)d_in[14], *r2b1=(const float*)d_in[15];
  const float* r2w2=(const float*)d_in[16], *r2b2=(const float*)d_in[17];
  const float* r3w1=(const float*)d_in[18], *r3b1=(const float*)d_in[19];
  const float* r3w2=(const float*)d_in[20], *r3b2=(const float*)d_in[21];
  const float* src_w  =(const float*)d_in[22];
  const float* ln_g   =(const float*)d_in[23];
  const float* ln_b   =(const float*)d_in[24];
  const float* out_w  =(const float*)d_in[25];
  const float* out_b  =(const float*)d_in[26];
  const float* v_scale=(const float*)d_in[27];
  const float* t_scale=(const float*)d_in[28];

  float* h_ws = (float*)d_ws;                    // 512*128 f32 = 256 KiB
  float* out_s = (float*)d_out;
  float* out_v = out_s + (size_t)Bb*Nn*Dd;
  float* out_t = out_v + (size_t)Bb*Nn*3*Dd;

  hproj_kernel<<<dim3(Bb*Nn), dim3(Dd), 0, stream>>>(node_s, src_w, h_ws);
  se3_mfma3<<<dim3(Bb*Nn), dim3(256), 0, stream>>>(
      node_v, rbf, r_hat, maskp,
      r0w1,r0b1,r0w2,r0b2, r1w1,r1b1,r1w2,r1b2,
      r2w1,r2b1,r2w2,r2b2, r3w1,r3b1,r3w2,r3b2,
      ln_g, ln_b, out_w, out_b, v_scale, t_scale,
      h_ws, out_s, out_v, out_t);
}